// Round 13
// baseline (251.651 us; speedup 1.0000x reference)
//
#include <hip/hip_runtime.h>
#include <math.h>

#define NUM_AGENTS   128
#define NUM_HIVES    64
#define NUM_ENTITIES 192
#define BPB 4   // batches per block = waves per block

// One WAVE per batch element. 256 threads = 4 waves = 4 batches; grid = B/4.
// Hot loop has ZERO cross-lane ops: each lane serially argmaxes 2 agent rows
// in registers (strict > keeps jnp.argmax first-index tie-break).
// Per-batch: counts via per-wave LDS atomics; hv gathered from a register
// via one __shfl per agent; 18 shuffle ops total in the epilogue reductions.
__global__ __launch_bounds__(256) void bee_kernel(
    const float* __restrict__ movements,    // (B, 192, 2)
    const float* __restrict__ votes,        // (B, 128, 64)
    const float* __restrict__ hive_values,  // (B, 64, 1)
    float* __restrict__ ws_partial,         // (B,)
    float* __restrict__ out,                // [0]=scalar, [1..B]=max_freq
    int B)
{
    const int tid  = threadIdx.x;
    const int lane = tid & 63;
    const int wave = tid >> 6;
    const int b    = blockIdx.x * BPB + wave;   // wave-uniform

    __shared__ int counts[BPB][NUM_HIVES];

    counts[wave][lane] = 0;   // zero own wave's 64 counters (1 lane each)

    float hv_reg = 0.0f, mc = 0.0f, bv0 = -INFINITY, bv1 = -INFINITY;
    int bi0 = 0, bi1 = 0;

    if (b < B) {
        // hive value for hive==lane kept in register; gathered later via shfl
        hv_reg = hive_values[(size_t)b * NUM_HIVES + lane];

        // movement cost: 192 entities = 3 coalesced float2 loads per lane
        const float2* mv = (const float2*)movements + (size_t)b * NUM_ENTITIES;
        float2 m0 = mv[lane];
        float2 m1 = mv[lane + 64];
        float2 m2 = mv[lane + 128];
        mc = sqrtf(m0.x*m0.x + m0.y*m0.y)
           + sqrtf(m1.x*m1.x + m1.y*m1.y)
           + sqrtf(m2.x*m2.x + m2.y*m2.y);

        // two agent rows per lane: agents (lane) and (lane+64)
        const float4* r0 = (const float4*)(votes + ((size_t)b * NUM_AGENTS + lane)      * NUM_HIVES);
        const float4* r1 = (const float4*)(votes + ((size_t)b * NUM_AGENTS + lane + 64) * NUM_HIVES);

        #pragma unroll
        for (int k = 0; k < 16; ++k) {
            float4 v0 = r0[k];
            float4 v1 = r1[k];
            if (v0.x > bv0) { bv0 = v0.x; bi0 = k*4 + 0; }
            if (v0.y > bv0) { bv0 = v0.y; bi0 = k*4 + 1; }
            if (v0.z > bv0) { bv0 = v0.z; bi0 = k*4 + 2; }
            if (v0.w > bv0) { bv0 = v0.w; bi0 = k*4 + 3; }
            if (v1.x > bv1) { bv1 = v1.x; bi1 = k*4 + 0; }
            if (v1.y > bv1) { bv1 = v1.y; bi1 = k*4 + 1; }
            if (v1.z > bv1) { bv1 = v1.z; bi1 = k*4 + 2; }
            if (v1.w > bv1) { bv1 = v1.w; bi1 = k*4 + 3; }
        }
    }
    __syncthreads();   // counters zeroed

    float vsum = 0.0f;
    if (b < B) {
        atomicAdd(&counts[wave][bi0], 1);
        atomicAdd(&counts[wave][bi1], 1);
        // gather hv[besti] from the register file (wave-uniform branch -> safe)
        vsum = __shfl(hv_reg, bi0, 64) + __shfl(hv_reg, bi1, 64);
    }
    __syncthreads();   // atomics visible

    if (b < B) {
        int c = counts[wave][lane];
        #pragma unroll
        for (int off = 32; off > 0; off >>= 1) {
            c     = max(c, __shfl_xor(c, off, 64));
            mc   += __shfl_xor(mc,   off, 64);
            vsum += __shfl_xor(vsum, off, 64);
        }
        if (lane == 0) {
            float mf = (float)c * (1.0f / (float)NUM_AGENTS);
            out[1 + b] = mf;
            // discount = 100 / (1 + exp(30*(mf - 0.7)))
            float discount = 100.0f / (1.0f + expf(30.0f * (mf - 0.7f)));
            ws_partial[b] = mc - vsum / discount;
        }
    }
}

// Single block reduces B partials -> out[0]. Deterministic, no atomics.
__global__ __launch_bounds__(256) void reduce_kernel(
    const float* __restrict__ ws_partial, float* __restrict__ out, int B)
{
    const int tid  = threadIdx.x;
    const int lane = tid & 63;
    const int wave = tid >> 6;
    __shared__ float p_s[4];

    float s = 0.0f;
    const float4* w4 = (const float4*)ws_partial;
    for (int i = tid; i < B / 4; i += 256) {
        float4 v = w4[i];
        s += (v.x + v.y) + (v.z + v.w);
    }
    #pragma unroll
    for (int off = 32; off > 0; off >>= 1) s += __shfl_down(s, off, 64);
    if (lane == 0) p_s[wave] = s;
    __syncthreads();
    if (tid == 0) out[0] = p_s[0] + p_s[1] + p_s[2] + p_s[3];
}

extern "C" void kernel_launch(void* const* d_in, const int* in_sizes, int n_in,
                              void* d_out, int out_size, void* d_ws, size_t ws_size,
                              hipStream_t stream) {
    const float* movements   = (const float*)d_in[0];
    // d_in[1] = utterances (unused by reference)
    const float* votes       = (const float*)d_in[2];
    const float* hive_values = (const float*)d_in[3];
    // d_in[4] = locations (unused by reference)
    float* out = (float*)d_out;
    float* ws_partial = (float*)d_ws;   // B floats of scratch

    const int B = in_sizes[3] / NUM_HIVES;   // 4096

    const int grid = (B + BPB - 1) / BPB;    // 1024
    bee_kernel<<<grid, 256, 0, stream>>>(movements, votes, hive_values, ws_partial, out, B);
    reduce_kernel<<<1, 256, 0, stream>>>(ws_partial, out, B);
}

// Round 14
// 233.428 us; speedup vs baseline: 1.0781x; 1.0781x over previous
//
#include <hip/hip_runtime.h>
#include <math.h>

#define NUM_AGENTS   128
#define NUM_HIVES    64
#define NUM_ENTITIES 192

// One block per batch element. 256 threads = 4 waves.
// Writes per-block scalar partial to ws_partial[b] (NO same-address atomics),
// and out[1 + b] = max_freq[b]. A second kernel reduces ws_partial -> out[0].
__global__ __launch_bounds__(256) void bee_kernel(
    const float* __restrict__ movements,    // (B, 192, 2)
    const float* __restrict__ votes,        // (B, 128, 64)
    const float* __restrict__ hive_values,  // (B, 64, 1)
    float* __restrict__ ws_partial,         // (B,)
    float* __restrict__ out)
{
    const int b    = blockIdx.x;
    const int tid  = threadIdx.x;
    const int lane = tid & 63;
    const int wave = tid >> 6;

    __shared__ float hv[NUM_HIVES];
    __shared__ int   counts[NUM_HIVES];
    __shared__ float mc_s[4];
    __shared__ float vs_s[4];

    if (tid < NUM_HIVES) {
        hv[tid]     = hive_values[(size_t)b * NUM_HIVES + tid];
        counts[tid] = 0;
    }
    __syncthreads();

    // ---- movement cost partial: 192 entities, float2 coalesced ----
    float mc = 0.0f;
    if (tid < NUM_ENTITIES) {
        float2 m = ((const float2*)movements)[(size_t)b * NUM_ENTITIES + tid];
        mc = sqrtf(m.x * m.x + m.y * m.y);
    }

    // ---- per-agent argmax over 64 hives ----
    // 16 lanes per agent, each lane loads a float4; butterfly argmax in-group.
    const int grp = lane >> 4;   // 0..3: which agent within the wave
    const int gl  = lane & 15;   // lane within the 16-lane group
    const float4* vbase = (const float4*)(votes + (size_t)b * NUM_AGENTS * NUM_HIVES);

    float vsum = 0.0f;
    #pragma unroll
    for (int iter = 0; iter < 8; ++iter) {
        const int a = iter * 16 + wave * 4 + grp;
        float4 v = vbase[a * 16 + gl];

        float bestv = v.x; int besti = gl * 4;
        if (v.y > bestv) { bestv = v.y; besti = gl * 4 + 1; }
        if (v.z > bestv) { bestv = v.z; besti = gl * 4 + 2; }
        if (v.w > bestv) { bestv = v.w; besti = gl * 4 + 3; }

        // butterfly argmax across the 16-lane group (xor 1,2,4,8 stays in-group)
        #pragma unroll
        for (int off = 1; off < 16; off <<= 1) {
            float ov = __shfl_xor(bestv, off, 64);
            int   oi = __shfl_xor(besti, off, 64);
            if (ov > bestv || (ov == bestv && oi < besti)) { bestv = ov; besti = oi; }
        }

        if (gl == 0) {
            atomicAdd(&counts[besti], 1);
            vsum += hv[besti];
        }
    }

    // ---- block reduction of mc and vsum ----
    #pragma unroll
    for (int off = 32; off > 0; off >>= 1) {
        mc   += __shfl_down(mc,   off, 64);
        vsum += __shfl_down(vsum, off, 64);
    }
    if (lane == 0) { mc_s[wave] = mc; vs_s[wave] = vsum; }
    __syncthreads();   // also makes counts[] atomics visible

    if (wave == 0) {
        int c = counts[lane];
        #pragma unroll
        for (int off = 32; off > 0; off >>= 1) {
            int oc = __shfl_down(c, off, 64);
            c = c > oc ? c : oc;
        }
        if (lane == 0) {
            float mc_t = mc_s[0] + mc_s[1] + mc_s[2] + mc_s[3];
            float vs_t = vs_s[0] + vs_s[1] + vs_s[2] + vs_s[3];
            float mf = (float)c / (float)NUM_AGENTS;
            out[1 + b] = mf;
            // discount = 100*(1 - sigmoid(30*(mf-0.7))) = 100 / (1 + exp(30*(mf-0.7)))
            float discount = 100.0f / (1.0f + expf(30.0f * (mf - 0.7f)));
            // per-block contribution: movement partial + (-value/discount)
            ws_partial[b] = mc_t - vs_t / discount;
        }
    }
}

// Single block reduces B partials -> out[0]. Deterministic, no atomics.
__global__ __launch_bounds__(256) void reduce_kernel(
    const float* __restrict__ ws_partial, float* __restrict__ out, int B)
{
    const int tid  = threadIdx.x;
    const int lane = tid & 63;
    const int wave = tid >> 6;
    __shared__ float p_s[4];

    float s = 0.0f;
    const float4* w4 = (const float4*)ws_partial;
    for (int i = tid; i < B / 4; i += 256) {
        float4 v = w4[i];
        s += (v.x + v.y) + (v.z + v.w);
    }
    #pragma unroll
    for (int off = 32; off > 0; off >>= 1) s += __shfl_down(s, off, 64);
    if (lane == 0) p_s[wave] = s;
    __syncthreads();
    if (tid == 0) out[0] = p_s[0] + p_s[1] + p_s[2] + p_s[3];
}

extern "C" void kernel_launch(void* const* d_in, const int* in_sizes, int n_in,
                              void* d_out, int out_size, void* d_ws, size_t ws_size,
                              hipStream_t stream) {
    const float* movements   = (const float*)d_in[0];
    // d_in[1] = utterances (unused by reference)
    const float* votes       = (const float*)d_in[2];
    const float* hive_values = (const float*)d_in[3];
    // d_in[4] = locations (unused by reference)
    float* out = (float*)d_out;
    float* ws_partial = (float*)d_ws;   // B floats of scratch

    const int B = in_sizes[3] / NUM_HIVES;   // 4096

    bee_kernel<<<B, 256, 0, stream>>>(movements, votes, hive_values, ws_partial, out);
    reduce_kernel<<<1, 256, 0, stream>>>(ws_partial, out, B);
}

// Round 16
// 232.078 us; speedup vs baseline: 1.0843x; 1.0058x over previous
//
#include <hip/hip_runtime.h>
#include <math.h>

#define NUM_AGENTS   128
#define NUM_HIVES    64
#define NUM_ENTITIES 192

// One block per batch element. 256 threads = 4 waves.
// 2 lanes per agent: each lane serially argmaxes 32 contiguous floats in
// registers (zero cross-lane ops), then ONE shfl_xor merge per agent.
// DS-pipe ops per thread: ~19 total (was ~97 with the 16-lane butterfly).
__global__ __launch_bounds__(256) void bee_kernel(
    const float* __restrict__ movements,    // (B, 192, 2)
    const float* __restrict__ votes,        // (B, 128, 64)
    const float* __restrict__ hive_values,  // (B, 64, 1)
    float* __restrict__ ws_partial,         // (B,)
    float* __restrict__ out)                // [0]=scalar, [1..B]=max_freq
{
    const int b    = blockIdx.x;
    const int tid  = threadIdx.x;
    const int lane = tid & 63;
    const int wave = tid >> 6;

    __shared__ float hv[NUM_HIVES];
    __shared__ int   counts[NUM_HIVES];
    __shared__ float mc_s[4];
    __shared__ float vs_s[4];

    if (tid < NUM_HIVES) {
        hv[tid]     = hive_values[(size_t)b * NUM_HIVES + tid];
        counts[tid] = 0;
    }
    __syncthreads();

    // ---- movement cost partial: 192 entities, float2 coalesced ----
    float mc = 0.0f;
    if (tid < NUM_ENTITIES) {
        float2 m = ((const float2*)movements)[(size_t)b * NUM_ENTITIES + tid];
        mc = sqrtf(m.x * m.x + m.y * m.y);
    }

    // ---- per-agent argmax: agent = tid>>1, half row (32 floats) per lane ----
    const int agent = tid >> 1;     // 0..127, one pass covers all agents
    const int half  = tid & 1;      // 0: hives 0..31, 1: hives 32..63
    const float4* row = (const float4*)(votes + (size_t)b * NUM_AGENTS * NUM_HIVES)
                        + agent * 16 + half * 8;

    // serial in-register argmax over 32 floats (strict > = first-index ties)
    float bv = -INFINITY;
    int   bi = 0;
    #pragma unroll
    for (int k = 0; k < 8; ++k) {
        float4 v = row[k];
        int base = half * 32 + k * 4;
        if (v.x > bv) { bv = v.x; bi = base + 0; }
        if (v.y > bv) { bv = v.y; bi = base + 1; }
        if (v.z > bv) { bv = v.z; bi = base + 2; }
        if (v.w > bv) { bv = v.w; bi = base + 3; }
    }

    // single merge step with the partner lane (xor 1); lower index wins ties
    {
        float ov = __shfl_xor(bv, 1, 64);
        int   oi = __shfl_xor(bi, 1, 64);
        if (ov > bv || (ov == bv && oi < bi)) { bv = ov; bi = oi; }
    }

    float vsum = 0.0f;
    if (half == 0) {
        atomicAdd(&counts[bi], 1);
        vsum = hv[bi];
    }

    // ---- block reduction of mc and vsum ----
    #pragma unroll
    for (int off = 32; off > 0; off >>= 1) {
        mc   += __shfl_down(mc,   off, 64);
        vsum += __shfl_down(vsum, off, 64);
    }
    if (lane == 0) { mc_s[wave] = mc; vs_s[wave] = vsum; }
    __syncthreads();   // also makes counts[] atomics visible

    if (wave == 0) {
        int c = counts[lane];
        #pragma unroll
        for (int off = 32; off > 0; off >>= 1) {
            int oc = __shfl_down(c, off, 64);
            c = c > oc ? c : oc;
        }
        if (lane == 0) {
            float mc_t = mc_s[0] + mc_s[1] + mc_s[2] + mc_s[3];
            float vs_t = vs_s[0] + vs_s[1] + vs_s[2] + vs_s[3];
            float mf = (float)c / (float)NUM_AGENTS;
            out[1 + b] = mf;
            // discount = 100*(1 - sigmoid(30*(mf-0.7))) = 100 / (1 + exp(30*(mf-0.7)))
            float discount = 100.0f / (1.0f + expf(30.0f * (mf - 0.7f)));
            ws_partial[b] = mc_t - vs_t / discount;
        }
    }
}

// Single block reduces B partials -> out[0]. Deterministic, no atomics.
__global__ __launch_bounds__(256) void reduce_kernel(
    const float* __restrict__ ws_partial, float* __restrict__ out, int B)
{
    const int tid  = threadIdx.x;
    const int lane = tid & 63;
    const int wave = tid >> 6;
    __shared__ float p_s[4];

    float s = 0.0f;
    const float4* w4 = (const float4*)ws_partial;
    for (int i = tid; i < B / 4; i += 256) {
        float4 v = w4[i];
        s += (v.x + v.y) + (v.z + v.w);
    }
    #pragma unroll
    for (int off = 32; off > 0; off >>= 1) s += __shfl_down(s, off, 64);
    if (lane == 0) p_s[wave] = s;
    __syncthreads();
    if (tid == 0) out[0] = p_s[0] + p_s[1] + p_s[2] + p_s[3];
}

extern "C" void kernel_launch(void* const* d_in, const int* in_sizes, int n_in,
                              void* d_out, int out_size, void* d_ws, size_t ws_size,
                              hipStream_t stream) {
    const float* movements   = (const float*)d_in[0];
    // d_in[1] = utterances (unused by reference)
    const float* votes       = (const float*)d_in[2];
    const float* hive_values = (const float*)d_in[3];
    // d_in[4] = locations (unused by reference)
    float* out = (float*)d_out;
    float* ws_partial = (float*)d_ws;   // B floats of scratch

    const int B = in_sizes[3] / NUM_HIVES;   // 4096

    bee_kernel<<<B, 256, 0, stream>>>(movements, votes, hive_values, ws_partial, out);
    reduce_kernel<<<1, 256, 0, stream>>>(ws_partial, out, B);
}